// Round 8
// baseline (762.263 us; speedup 1.0000x reference)
//
#include <hip/hip_runtime.h>

#define NEGV (-10000.0f)

constexpr int Bb = 512;
constexpr int Ss = 1024;
constexpr int Tt = 64;

typedef __attribute__((address_space(1))) const unsigned int guint_t;
typedef __attribute__((address_space(3))) unsigned int luint_t;

// One block (256 threads = 4 waves) per batch. Wave w owns prev-tags [16w,16w+16).
// Lane l owns next-tag l. Critical path is value-only; argmax resolved one step
// late (lag pipeline) by wave 0 from per-wave packed bytes. Exact tie-breaks.
__global__ __launch_bounds__(256, 2) void viterbi_fused(
    const float* __restrict__ feats,      // [B,S,T]
    const float* __restrict__ trans,      // [T,T] (next, prev)
    float* __restrict__ path_score,       // [B]
    float* __restrict__ best_path)        // [B,S] tags as float
{
    __shared__ float ftile[2][8][Tt];           // 4 KB   feats tiles (8 steps)
    __shared__ float vpart[2][4][Tt];           // 2 KB   per-wave value partials (stride-4, conflict-free)
    __shared__ unsigned int ipart[2][Tt];       // 512 B  byte w = wave w's prev idx or 0xFF
    __shared__ unsigned char bp_lds[Ss][Tt];    // 64 KB  backpointers
    __shared__ unsigned char ccomp[32][Tt];     // 2 KB   composed chunk jumps
    __shared__ int btags[32];                   // 128 B

    const int b    = blockIdx.x;
    const int tid  = threadIdx.x;
    const int wid  = tid >> 6;
    const int lane = tid & 63;
    const int base = wid << 4;                  // this wave's prev range start

    const float* fb = feats + (size_t)b * (Ss * Tt);

    // Per-lane transition slice: trans[lane][base .. base+16)  (16 VGPRs)
    float trow[16];
    {
        const float* tr = trans + lane * Tt + base;
        float4* tv = (float4*)trow;
        tv[0] = *(const float4*)(tr + 0);
        tv[1] = *(const float4*)(tr + 4);
        tv[2] = *(const float4*)(tr + 8);
        tv[3] = *(const float4*)(tr + 12);
    }
    float tend = trans[63 * Tt + lane];         // terminal row (END_IX = 63)

    // Prologue: stage tile 0 into LDS via async DMA (wave 3; wave 0 does lag work).
    if (wid == 3) {
#pragma unroll
        for (int i = 0; i < 2; ++i)
            __builtin_amdgcn_global_load_lds(
                (guint_t*)(fb + i * 256 + lane * 4),
                (luint_t*)((unsigned int*)&ftile[0][0][0] + i * 256),
                16, 0, 0);
        asm volatile("s_waitcnt vmcnt(0)" ::: "memory");
    }
    __syncthreads();

    float fv  = (lane == 62) ? 0.0f : NEGV;     // START_IX = 62
    int  comp = lane;                           // wave 0: composed jumps (lagged)

    for (int t = 0; t < 128; ++t) {
        if (wid == 3 && t + 1 < 128) {
            const float* src = fb + (size_t)(t + 1) * 512;
            unsigned int* dst = (unsigned int*)&ftile[(t + 1) & 1][0][0];
#pragma unroll
            for (int i = 0; i < 2; ++i)
                __builtin_amdgcn_global_load_lds(
                    (guint_t*)(src + i * 256 + lane * 4),
                    (luint_t*)(dst + i * 256),
                    16, 0, 0);
        }
#pragma unroll
        for (int i = 0; i < 8; ++i) {
            const int s = t * 8 + i;
            const int p = s & 1;
            float featv = ftile[t & 1][i][lane];

            // 16 candidates: fv[base+j] via intra-wave readlane (no LDS hop).
            float c[16];
#pragma unroll
            for (int j = 0; j < 16; ++j) {
                float g = __int_as_float(
                    __builtin_amdgcn_readlane(__float_as_int(fv), base + j));
                c[j] = g + trow[j];
            }
            // Value-only max tree (v_max3-friendly; max is order-exact).
            float a0 = fmaxf(fmaxf(c[0],  c[1]),  c[2]);
            float a1 = fmaxf(fmaxf(c[3],  c[4]),  c[5]);
            float a2 = fmaxf(fmaxf(c[6],  c[7]),  c[8]);
            float a3 = fmaxf(fmaxf(c[9],  c[10]), c[11]);
            float a4 = fmaxf(fmaxf(c[12], c[13]), c[14]);
            float m  = fmaxf(fmaxf(fmaxf(a0, a1), fmaxf(a2, a3)), fmaxf(a4, c[15]));

            vpart[p][wid][lane] = m;

            // Tile boundary: pin ftile read pre-barrier; drain DMA (wave 3).
            if (i == 7) {
                asm volatile("" : "+v"(featv));
                if (wid == 3) asm volatile("s_waitcnt vmcnt(0)" ::: "memory");
            }
            __syncthreads();

            float v0 = vpart[p][0][lane];
            float v1 = vpart[p][1][lane];
            float v2 = vpart[p][2][lane];
            float v3 = vpart[p][3][lane];
            float mb = fmaxf(fmaxf(v0, v1), fmaxf(v2, v3));

            // Shadow argmax: first local j with c[j]==mb (exact first-max).
            int jf = 15;
#pragma unroll
            for (int j = 14; j >= 0; --j) jf = (c[j] == mb) ? j : jf;
            unsigned int byte = (m == mb) ? (unsigned)(base + jf) : 0xFFu;
            ((unsigned char*)&ipart[p][0])[lane * 4 + wid] = (unsigned char)byte;

            // Wave 0: lagged bp resolve for step s-1 (buffer 1-p, barrier-separated).
            if (wid == 0 && s > 0) {
                unsigned int u = ipart[1 - p][lane];
                int b0 = u & 0xFF, b1 = (u >> 8) & 0xFF, b2 = (u >> 16) & 0xFF;
                int b3 = u >> 24;
                int ib = (b0 != 0xFF) ? b0 : (b1 != 0xFF) ? b1 : (b2 != 0xFF) ? b2 : b3;
                bp_lds[s - 1][lane] = (unsigned char)ib;
                comp = __shfl(comp, ib);
                if (((s - 1) & 31) == 31) {
                    ccomp[(s - 1) >> 5][lane] = (unsigned char)comp;
                    comp = lane;
                }
            }
            fv = mb + featv;
        }
    }

    __syncthreads();   // make s=1023's ipart[1] visible

    if (wid == 0) {
        // Resolve final step s = 1023 (parity 1), dump chunk 31.
        {
            unsigned int u = ipart[1][lane];
            int b0 = u & 0xFF, b1 = (u >> 8) & 0xFF, b2 = (u >> 16) & 0xFF;
            int b3 = u >> 24;
            int ib = (b0 != 0xFF) ? b0 : (b1 != 0xFF) ? b1 : (b2 != 0xFF) ? b2 : b3;
            bp_lds[1023][lane] = (unsigned char)ib;
            comp = __shfl(comp, ib);
            ccomp[31][lane] = (unsigned char)comp;
        }
        // Terminal: fv + trans[END][lane]; wave argmax (tie -> lower index).
        float mr = fv + tend; int ir = lane;
#pragma unroll
        for (int off = 32; off >= 1; off >>= 1) {
            float mo = __shfl_xor(mr, off);
            int   io = __shfl_xor(ir, off);
            bool take = (mo > mr) || ((mo == mr) && (io < ir));
            mr = take ? mo : mr; ir = take ? io : ir;
        }
        if (lane == 0) {
            path_score[b] = mr;
            int tag = ir;
            for (int c2 = 31; c2 >= 0; --c2) {  // serial chunk-tag chase in LDS
                btags[c2] = tag;
                tag = ccomp[c2][tag];
            }
        }
    }
    __syncthreads();

    // Parallel in-chunk backtrace: lane c handles steps [32c, 32c+32).
    if (wid == 0 && lane < 32) {
        int tag = btags[lane];
        float* op = best_path + (size_t)b * Ss + lane * 32;
        for (int i = 31; i >= 0; --i) {
            op[i] = (float)tag;
            tag = bp_lds[lane * 32 + i][tag];
        }
    }
}

extern "C" void kernel_launch(void* const* d_in, const int* in_sizes, int n_in,
                              void* d_out, int out_size, void* d_ws, size_t ws_size,
                              hipStream_t stream) {
    const float* feats = (const float*)d_in[0];   // [512,1024,64] f32
    const float* trans = (const float*)d_in[1];   // [64,64] f32

    float* path_score = (float*)d_out;            // [512]
    float* best_path  = (float*)d_out + Bb;       // [512,1024] tags as float

    viterbi_fused<<<Bb, 256, 0, stream>>>(feats, trans, path_score, best_path);
}